// Round 9
// baseline (381.814 us; speedup 1.0000x reference)
//
#include <hip/hip_runtime.h>

typedef __bf16 bf16;
typedef bf16 bf16x4 __attribute__((ext_vector_type(4)));
typedef bf16 bf16x8 __attribute__((ext_vector_type(8)));
typedef float f32x4 __attribute__((ext_vector_type(4)));

#define D_MODEL 1024
#define NHEAD   16
#define D_K     64
#define BATCH   8
#define SEQL    1024
#define MROWS   (BATCH*SEQL)   // 8192
#define NT      (SEQL / 64)

// ---------------- f32 -> bf16 conversion (7 arrays in one launch) ----------------
struct Cvt7 {
    const float* s[7];
    bf16*        d[7];
    int          n[7];
};

__global__ __launch_bounds__(256) void cvt7_kernel(Cvt7 a) {
    const int y = blockIdx.y;
    const float* __restrict__ src = a.s[y];
    bf16* __restrict__ dst = a.d[y];
    const int n4 = a.n[y] >> 2;
    const int stride = gridDim.x * blockDim.x;
    for (int i = blockIdx.x * blockDim.x + threadIdx.x; i < n4; i += stride) {
        float4 v = ((const float4*)src)[i];
        bf16x4 o = { (bf16)v.x, (bf16)v.y, (bf16)v.z, (bf16)v.w };
        ((bf16x4*)dst)[i] = o;
    }
}

// ---------------- GEMM core (R1-proven m97 structure): C = A * B^T ----------------
// 128x128 tile, BK=32, 4 waves (2x2 of 64x64), global_load_lds w=16.
// R2 lesson: 256x256 tile regressed at N=1024 (4 col-tiles -> 1.5 blk/CU imbalance).
#define BM 128
#define BN 128
#define BK 32

__device__ __forceinline__ void gemm_core(const bf16* __restrict__ A, const bf16* __restrict__ B,
                                          int bm, int bn, int K,
                                          bf16* lA, bf16* lB, f32x4 (&acc)[4][4]) {
    const int t = threadIdx.x;
    const int lane = t & 63, w = t >> 6;
    const int wr = w >> 1, wc = w & 1;
    const int r = lane & 15, kb = lane >> 4;

    for (int k0 = 0; k0 < K; k0 += BK) {
        __syncthreads();
        #pragma unroll
        for (int i = 0; i < 2; ++i) {
            const int off = i * 4096 + w * 1024 + lane * 16;
            const int row = off >> 6;
            const int cb  = off & 63;
            const bf16* srcA = A + (size_t)(bm + row) * K + k0 + (cb >> 1);
            const bf16* srcB = B + (size_t)(bn + row) * K + k0 + (cb >> 1);
            __builtin_amdgcn_global_load_lds(
                (const __attribute__((address_space(1))) unsigned int*)srcA,
                (__attribute__((address_space(3))) unsigned int*)((char*)lA + i * 4096 + w * 1024),
                16, 0, 0);
            __builtin_amdgcn_global_load_lds(
                (const __attribute__((address_space(1))) unsigned int*)srcB,
                (__attribute__((address_space(3))) unsigned int*)((char*)lB + i * 4096 + w * 1024),
                16, 0, 0);
        }
        __syncthreads();

        bf16x8 af[4], bfr[4];
        #pragma unroll
        for (int m = 0; m < 4; ++m)
            af[m] = *(const bf16x8*)(lA + (wr * 64 + m * 16 + r) * BK + kb * 8);
        #pragma unroll
        for (int n = 0; n < 4; ++n)
            bfr[n] = *(const bf16x8*)(lB + (wc * 64 + n * 16 + r) * BK + kb * 8);
        #pragma unroll
        for (int m = 0; m < 4; ++m)
            #pragma unroll
            for (int n = 0; n < 4; ++n)
                acc[m][n] = __builtin_amdgcn_mfma_f32_16x16x32_bf16(af[m], bfr[n], acc[m][n], 0, 0, 0);
    }
}

// ---------------- Q/K/V projections (one launch, z = 0/1/2) ----------------
__global__ __launch_bounds__(256) void proj3_kernel(
        const bf16* __restrict__ xq, const bf16* __restrict__ xk, const bf16* __restrict__ xv,
        const bf16* __restrict__ Wqb, const bf16* __restrict__ Wkb, const bf16* __restrict__ Wvb,
        const float* __restrict__ bq, const float* __restrict__ bk, const float* __restrict__ bv,
        bf16* __restrict__ Qp, bf16* __restrict__ Kp, bf16* __restrict__ Vt) {
    __shared__ bf16 lA[BM * BK], lB[BN * BK];
    const int z = blockIdx.z;
    const bf16* A    = (z == 0) ? xq  : (z == 1) ? xk  : xv;
    const bf16* Bm   = (z == 0) ? Wqb : (z == 1) ? Wkb : Wvb;
    const float* bias = (z == 0) ? bq : (z == 1) ? bk  : bv;
    const int bm = blockIdx.x * BM, bn = blockIdx.y * BN;

    f32x4 acc[4][4] = {};
    gemm_core(A, Bm, bm, bn, D_MODEL, lA, lB, acc);

    const int lane = threadIdx.x & 63, w = threadIdx.x >> 6;
    const int wr = w >> 1, wc = w & 1, r = lane & 15, g = lane >> 4;
    #pragma unroll
    for (int n = 0; n < 4; ++n) {
        const int col = bn + wc * 64 + n * 16 + r;
        const float bvl = bias[col];
        const int h = col >> 6, d = col & 63;
        #pragma unroll
        for (int m = 0; m < 4; ++m) {
            #pragma unroll
            for (int j = 0; j < 4; ++j) {
                const int row = bm + wr * 64 + m * 16 + g * 4 + j;
                const float v = acc[m][n][j] + bvl;
                const int b = row >> 10, s = row & (SEQL - 1);
                const int bh = b * NHEAD + h;
                if (z == 0) {
                    Qp[((size_t)bh * SEQL + s) * D_K + d] = (bf16)v;
                } else if (z == 1) {
                    Kp[((size_t)bh * SEQL + s) * D_K + d] = (bf16)v;
                } else {
                    Vt[((size_t)bh * D_K + d) * SEQL + s] = (bf16)v;
                }
            }
        }
    }
}

// ---------------- output projection: out = AO * Wo^T + bo (f32 out) ----------------
__global__ __launch_bounds__(256) void outproj_kernel(
        const bf16* __restrict__ AO, const bf16* __restrict__ Wob,
        const float* __restrict__ bo, float* __restrict__ out) {
    __shared__ bf16 lA[BM * BK], lB[BN * BK];
    const int bm = blockIdx.x * BM, bn = blockIdx.y * BN;
    f32x4 acc[4][4] = {};
    gemm_core(AO, Wob, bm, bn, D_MODEL, lA, lB, acc);

    const int lane = threadIdx.x & 63, w = threadIdx.x >> 6;
    const int wr = w >> 1, wc = w & 1, r = lane & 15, g = lane >> 4;
    #pragma unroll
    for (int n = 0; n < 4; ++n) {
        const int col = bn + wc * 64 + n * 16 + r;
        const float bvl = bo[col];
        #pragma unroll
        for (int m = 0; m < 4; ++m)
            #pragma unroll
            for (int j = 0; j < 4; ++j) {
                const int row = bm + wr * 64 + m * 16 + g * 4 + j;
                out[(size_t)row * D_MODEL + col] = acc[m][n][j] + bvl;
            }
    }
}

// ---------------- fused masked flash attention: R6 + T14 mask reg-prefetch ----------------
// R6 (proven): block-level LDS staging, line-granular global access, 40KB LDS.
// R7 lesson: full dbuf (72KB -> 2 blk/CU) regressed — occupancy beats pipelining here.
// R8 lesson: XCD remap neutral (kept, harmless); K/V re-reads already L2/L3-absorbed.
// R9: T14 async-STAGE split on the MASK (the only HBM-cold stream): load mask tile t+1
// into 16 VGPRs (same line-granular pattern) during tile t's compute; ds_write into mbuf
// at top of t+1. Raw s_barrier + manual "vmcnt(4) lgkmcnt(0)" (counted vmcnt, T4) keeps
// those 4 loads in flight across the barrier — __syncthreads would drain them (vmcnt 0).
// sched_barrier(0) pins K/V-gload_lds-before-mask-load issue order so vmcnt(4) == K/V done.
// Zero extra LDS -> 4 blocks/CU (40KB x 4 = 160KB exactly).
__global__ __launch_bounds__(256, 4) void attn_kernel(
        const bf16* __restrict__ Qp, const bf16* __restrict__ Kp, const bf16* __restrict__ Vt,
        const unsigned int* __restrict__ mask, bf16* __restrict__ AO) {
    __shared__ char kbuf[8192];            // K tile [64 s][128B], chunk-swizzled
    __shared__ char vbuf[8192];            // V^T tile [64 d][128B], chunk-swizzled
    __shared__ char mbuf[16384];           // mask tile [64 q][256B], chunk-swizzled
    __shared__ bf16 plds[4][16 * 64];      // per-wave P tile (2 KiB each) -> 40KB total
    const int lin = blockIdx.x + blockIdx.y * gridDim.x;
    const int xcd = lin & 7, pos = lin >> 3;
    const int bh  = xcd * 16 + (pos >> 4);
    const int qt  = pos & 15;
    const int b = bh >> 4, h = bh & 15;
    const int t = threadIdx.x, lane = t & 63, w = t >> 6;
    const int q0 = qt * 64;                // block q-tile; wave w owns rows w*16 + r
    const int r = lane & 15, g = lane >> 4;

    const char* __restrict__ Kb = (const char*)(Kp + (size_t)bh * SEQL * D_K);
    const char* __restrict__ Vb = (const char*)(Vt + (size_t)bh * D_K * SEQL);
    const char* __restrict__ Mb = (const char*)(mask + ((size_t)bh * SEQL + q0) * SEQL);

    // Q fragment (B-operand): lane holds Q[q=r][kk*32+g*8..+8]; loaded once
    const bf16* __restrict__ Qh = Qp + ((size_t)bh * SEQL + q0 + w * 16) * D_K;
    bf16x8 qf[2];
    #pragma unroll
    for (int kk = 0; kk < 2; ++kk)
        qf[kk] = *(const bf16x8*)(Qh + r * D_K + kk * 32 + g * 8);

    // mask prefetch registers: thread t holds rows i*16+(t>>4), chunk t&15 (16B each)
    uint4 mreg[4];
    #pragma unroll
    for (int i = 0; i < 4; ++i) {
        const int slot = i * 256 + t;
        const int row = slot >> 4, ch = slot & 15;
        mreg[i] = *(const uint4*)(Mb + (size_t)row * (SEQL * 4) + ((ch * 16) ^ ((row & 7) << 4)));
    }

    f32x4 o[4] = {};              // O^T: o[n][j] = O[q=r][d = n*16 + g*4 + j]
    float psum = 0.f;
    char* P = (char*)plds[w];
    const int swz = (r & 7) << 4;

    for (int tt = 0; tt < NT; ++tt) {
        const int s0 = tt * 64;
        const int sn = (tt + 1 < NT ? tt + 1 : tt) * 64;   // clamped tail keeps vmcnt counts const

        __builtin_amdgcn_s_barrier();   // barrier A: all waves done reading bufs of tt-1
        // ---- write prefetched mask regs -> mbuf (compiler inserts the vmcnt for mreg) ----
        #pragma unroll
        for (int i = 0; i < 4; ++i)
            *(uint4*)(mbuf + (i * 256 + t) * 16) = mreg[i];
        // ---- stage K/V for tile tt (4 x global_load_lds; linear dest, swizzled source) ----
        #pragma unroll
        for (int i = 0; i < 2; ++i) {
            const int slot = i * 256 + t;
            const int row = slot >> 3, ch = slot & 7;
            const char* srcK = Kb + (size_t)(s0 + row) * 128 + ((ch * 16) ^ ((row & 7) << 4));
            const char* srcV = Vb + (size_t)row * (SEQL * 2) + s0 * 2 + ((ch * 16) ^ ((row & 7) << 4));
            __builtin_amdgcn_global_load_lds(
                (const __attribute__((address_space(1))) unsigned int*)srcK,
                (__attribute__((address_space(3))) unsigned int*)(kbuf + i * 4096 + w * 1024),
                16, 0, 0);
            __builtin_amdgcn_global_load_lds(
                (const __attribute__((address_space(1))) unsigned int*)srcV,
                (__attribute__((address_space(3))) unsigned int*)(vbuf + i * 4096 + w * 1024),
                16, 0, 0);
        }
        __builtin_amdgcn_sched_barrier(0);   // pin: K/V issued BEFORE mask loads
        // ---- issue mask loads for tile tt+1 into regs (stay in flight across barrier) ----
        #pragma unroll
        for (int i = 0; i < 4; ++i) {
            const int slot = i * 256 + t;
            const int row = slot >> 4, ch = slot & 15;
            mreg[i] = *(const uint4*)(Mb + (size_t)row * (SEQL * 4) + sn * 4 + ((ch * 16) ^ ((row & 7) << 4)));
        }
        __builtin_amdgcn_sched_barrier(0);
        asm volatile("s_waitcnt vmcnt(4) lgkmcnt(0)" ::: "memory");   // K/V staged + mbuf written; mask(tt+1) in flight
        __builtin_amdgcn_s_barrier();   // barrier B: staging visible to all waves
        __builtin_amdgcn_sched_barrier(0);

        // ---- QK^T: sf[n][j] = S[q=r][kv = n*16 + g*4 + j] ----
        f32x4 sf[4] = {};
        __builtin_amdgcn_s_setprio(1);
        #pragma unroll
        for (int n = 0; n < 4; ++n) {
            #pragma unroll
            for (int kk = 0; kk < 2; ++kk) {
                const int krow = n * 16 + r;
                bf16x8 kf = *(const bf16x8*)(kbuf + krow * 128 + ((kk * 64 + g * 16) ^ swz));
                sf[n] = __builtin_amdgcn_mfma_f32_16x16x32_bf16(kf, qf[kk], sf[n], 0, 0, 0);
            }
        }
        __builtin_amdgcn_s_setprio(0);
        // ---- mask + exp (no max subtraction; masked lanes contribute exactly 0) ----
        const int mrow = w * 16 + r;
        #pragma unroll
        for (int n = 0; n < 4; ++n) {
            const uint4 mv = *(const uint4*)(mbuf + mrow * 256 + ((n * 64 + g * 16) ^ swz));
            const float p0 = mv.x ? __expf(sf[n][0] * 0.125f) : 0.f;
            const float p1 = mv.y ? __expf(sf[n][1] * 0.125f) : 0.f;
            const float p2 = mv.z ? __expf(sf[n][2] * 0.125f) : 0.f;
            const float p3 = mv.w ? __expf(sf[n][3] * 0.125f) : 0.f;
            psum += (p0 + p1) + (p2 + p3);
            bf16x4 pb = { (bf16)p0, (bf16)p1, (bf16)p2, (bf16)p3 };
            *(bf16x4*)(P + ((r * 128 + n * 32 + g * 8) ^ swz)) = pb;
        }
        // ---- PV: o[n] += V^T[d-block n] * P^T (P round-trip via per-wave LDS) ----
        bf16x8 pf0 = *(const bf16x8*)(P + ((r * 128 + 0 * 64 + g * 16) ^ swz));
        bf16x8 pf1 = *(const bf16x8*)(P + ((r * 128 + 1 * 64 + g * 16) ^ swz));
        __builtin_amdgcn_s_setprio(1);
        #pragma unroll
        for (int n = 0; n < 4; ++n) {
            const int vrow = n * 16 + r;
            bf16x8 vf0 = *(const bf16x8*)(vbuf + vrow * 128 + ((0 * 64 + g * 16) ^ swz));
            bf16x8 vf1 = *(const bf16x8*)(vbuf + vrow * 128 + ((1 * 64 + g * 16) ^ swz));
            o[n] = __builtin_amdgcn_mfma_f32_16x16x32_bf16(vf0, pf0, o[n], 0, 0, 0);
            o[n] = __builtin_amdgcn_mfma_f32_16x16x32_bf16(vf1, pf1, o[n], 0, 0, 0);
        }
        __builtin_amdgcn_s_setprio(0);
    }

    // deferred row-sum: lanes r, r+16, r+32, r+48 hold partials of row q=r
    psum += __shfl_xor(psum, 16);
    psum += __shfl_xor(psum, 32);
    const float inv = 1.0f / psum;

    const size_t rowbase = ((size_t)(b * SEQL + q0 + w * 16 + r)) * D_MODEL + h * D_K;
    #pragma unroll
    for (int n = 0; n < 4; ++n) {
        bf16x4 ob = { (bf16)(o[n][0] * inv), (bf16)(o[n][1] * inv),
                      (bf16)(o[n][2] * inv), (bf16)(o[n][3] * inv) };
        *(bf16x4*)(AO + rowbase + n * 16 + g * 4) = ob;
    }
}

// ---------------- launch ----------------
extern "C" void kernel_launch(void* const* d_in, const int* in_sizes, int n_in,
                              void* d_out, int out_size, void* d_ws, size_t ws_size,
                              hipStream_t stream) {
    const float* q    = (const float*)d_in[0];
    const float* k    = (const float*)d_in[1];
    const float* v    = (const float*)d_in[2];
    const unsigned int* mask = (const unsigned int*)d_in[3];
    const float* Wq = (const float*)d_in[4];
    const float* bq = (const float*)d_in[5];
    const float* Wk = (const float*)d_in[6];
    const float* bk = (const float*)d_in[7];
    const float* Wv = (const float*)d_in[8];
    const float* bv = (const float*)d_in[9];
    const float* Wo = (const float*)d_in[10];
    const float* bo = (const float*)d_in[11];

    char* ws = (char*)d_ws;
    const size_t MB = 1u << 20;
    bf16* qb  = (bf16*)(ws + 0 * MB);
    bf16* kb  = (bf16*)(ws + 16 * MB);
    bf16* vb  = (bf16*)(ws + 32 * MB);
    bf16* Wqb = (bf16*)(ws + 48 * MB);
    bf16* Wkb = (bf16*)(ws + 50 * MB);
    bf16* Wvb = (bf16*)(ws + 52 * MB);
    bf16* Wob = (bf16*)(ws + 54 * MB);
    bf16* Qp  = (bf16*)(ws + 56 * MB);
    bf16* Kp  = (bf16*)(ws + 72 * MB);
    bf16* Vt  = (bf16*)(ws + 88 * MB);
    bf16* AO  = (bf16*)(ws + 104 * MB);   // 120 MiB total

    Cvt7 c;
    c.s[0] = q;  c.d[0] = qb;  c.n[0] = MROWS * D_MODEL;
    c.s[1] = k;  c.d[1] = kb;  c.n[1] = MROWS * D_MODEL;
    c.s[2] = v;  c.d[2] = vb;  c.n[2] = MROWS * D_MODEL;
    c.s[3] = Wq; c.d[3] = Wqb; c.n[3] = D_MODEL * D_MODEL;
    c.s[4] = Wk; c.d[4] = Wkb; c.n[4] = D_MODEL * D_MODEL;
    c.s[5] = Wv; c.d[5] = Wvb; c.n[5] = D_MODEL * D_MODEL;
    c.s[6] = Wo; c.d[6] = Wob; c.n[6] = D_MODEL * D_MODEL;
    cvt7_kernel<<<dim3(1024, 7), 256, 0, stream>>>(c);

    proj3_kernel<<<dim3(MROWS / BM, D_MODEL / BN, 3), 256, 0, stream>>>(
        qb, kb, vb, Wqb, Wkb, Wvb, bq, bk, bv, Qp, Kp, Vt);

    attn_kernel<<<dim3(SEQL / 64, BATCH * NHEAD), 256, 0, stream>>>(Qp, Kp, Vt, mask, AO);

    outproj_kernel<<<dim3(MROWS / BM, D_MODEL / BN), 256, 0, stream>>>(AO, Wob, bo, (float*)d_out);
}

// Round 10
// 309.960 us; speedup vs baseline: 1.2318x; 1.2318x over previous
//
#include <hip/hip_runtime.h>

typedef __bf16 bf16;
typedef bf16 bf16x4 __attribute__((ext_vector_type(4)));
typedef bf16 bf16x8 __attribute__((ext_vector_type(8)));
typedef float f32x4 __attribute__((ext_vector_type(4)));

#define D_MODEL 1024
#define NHEAD   16
#define D_K     64
#define BATCH   8
#define SEQL    1024
#define MROWS   (BATCH*SEQL)   // 8192
#define NT      (SEQL / 64)

// ---------------- f32 -> bf16 conversion (7 arrays in one launch) ----------------
struct Cvt7 {
    const float* s[7];
    bf16*        d[7];
    int          n[7];
};

__global__ __launch_bounds__(256) void cvt7_kernel(Cvt7 a) {
    const int y = blockIdx.y;
    const float* __restrict__ src = a.s[y];
    bf16* __restrict__ dst = a.d[y];
    const int n4 = a.n[y] >> 2;
    const int stride = gridDim.x * blockDim.x;
    for (int i = blockIdx.x * blockDim.x + threadIdx.x; i < n4; i += stride) {
        float4 v = ((const float4*)src)[i];
        bf16x4 o = { (bf16)v.x, (bf16)v.y, (bf16)v.z, (bf16)v.w };
        ((bf16x4*)dst)[i] = o;
    }
}

// ---------------- GEMM core (R1-proven m97 structure): C = A * B^T ----------------
// 128x128 tile, BK=32, 4 waves (2x2 of 64x64), global_load_lds w=16.
// R2 lesson: 256x256 tile regressed at N=1024 (4 col-tiles -> 1.5 blk/CU imbalance).
#define BM 128
#define BN 128
#define BK 32

__device__ __forceinline__ void gemm_core(const bf16* __restrict__ A, const bf16* __restrict__ B,
                                          int bm, int bn, int K,
                                          bf16* lA, bf16* lB, f32x4 (&acc)[4][4]) {
    const int t = threadIdx.x;
    const int lane = t & 63, w = t >> 6;
    const int wr = w >> 1, wc = w & 1;
    const int r = lane & 15, kb = lane >> 4;

    for (int k0 = 0; k0 < K; k0 += BK) {
        __syncthreads();
        #pragma unroll
        for (int i = 0; i < 2; ++i) {
            const int off = i * 4096 + w * 1024 + lane * 16;
            const int row = off >> 6;
            const int cb  = off & 63;
            const bf16* srcA = A + (size_t)(bm + row) * K + k0 + (cb >> 1);
            const bf16* srcB = B + (size_t)(bn + row) * K + k0 + (cb >> 1);
            __builtin_amdgcn_global_load_lds(
                (const __attribute__((address_space(1))) unsigned int*)srcA,
                (__attribute__((address_space(3))) unsigned int*)((char*)lA + i * 4096 + w * 1024),
                16, 0, 0);
            __builtin_amdgcn_global_load_lds(
                (const __attribute__((address_space(1))) unsigned int*)srcB,
                (__attribute__((address_space(3))) unsigned int*)((char*)lB + i * 4096 + w * 1024),
                16, 0, 0);
        }
        __syncthreads();

        bf16x8 af[4], bfr[4];
        #pragma unroll
        for (int m = 0; m < 4; ++m)
            af[m] = *(const bf16x8*)(lA + (wr * 64 + m * 16 + r) * BK + kb * 8);
        #pragma unroll
        for (int n = 0; n < 4; ++n)
            bfr[n] = *(const bf16x8*)(lB + (wc * 64 + n * 16 + r) * BK + kb * 8);
        #pragma unroll
        for (int m = 0; m < 4; ++m)
            #pragma unroll
            for (int n = 0; n < 4; ++n)
                acc[m][n] = __builtin_amdgcn_mfma_f32_16x16x32_bf16(af[m], bfr[n], acc[m][n], 0, 0, 0);
    }
}

// ---------------- Q/K/V projections (one launch, z = 0/1/2) ----------------
__global__ __launch_bounds__(256) void proj3_kernel(
        const bf16* __restrict__ xq, const bf16* __restrict__ xk, const bf16* __restrict__ xv,
        const bf16* __restrict__ Wqb, const bf16* __restrict__ Wkb, const bf16* __restrict__ Wvb,
        const float* __restrict__ bq, const float* __restrict__ bk, const float* __restrict__ bv,
        bf16* __restrict__ Qp, bf16* __restrict__ Kp, bf16* __restrict__ Vt) {
    __shared__ bf16 lA[BM * BK], lB[BN * BK];
    const int z = blockIdx.z;
    const bf16* A    = (z == 0) ? xq  : (z == 1) ? xk  : xv;
    const bf16* Bm   = (z == 0) ? Wqb : (z == 1) ? Wkb : Wvb;
    const float* bias = (z == 0) ? bq : (z == 1) ? bk  : bv;
    const int bm = blockIdx.x * BM, bn = blockIdx.y * BN;

    f32x4 acc[4][4] = {};
    gemm_core(A, Bm, bm, bn, D_MODEL, lA, lB, acc);

    const int lane = threadIdx.x & 63, w = threadIdx.x >> 6;
    const int wr = w >> 1, wc = w & 1, r = lane & 15, g = lane >> 4;
    #pragma unroll
    for (int n = 0; n < 4; ++n) {
        const int col = bn + wc * 64 + n * 16 + r;
        const float bvl = bias[col];
        const int h = col >> 6, d = col & 63;
        #pragma unroll
        for (int m = 0; m < 4; ++m) {
            #pragma unroll
            for (int j = 0; j < 4; ++j) {
                const int row = bm + wr * 64 + m * 16 + g * 4 + j;
                const float v = acc[m][n][j] + bvl;
                const int b = row >> 10, s = row & (SEQL - 1);
                const int bh = b * NHEAD + h;
                if (z == 0) {
                    Qp[((size_t)bh * SEQL + s) * D_K + d] = (bf16)v;
                } else if (z == 1) {
                    Kp[((size_t)bh * SEQL + s) * D_K + d] = (bf16)v;
                } else {
                    Vt[((size_t)bh * D_K + d) * SEQL + s] = (bf16)v;
                }
            }
        }
    }
}

// ---------------- output projection: out = AO * Wo^T + bo (f32 out) ----------------
__global__ __launch_bounds__(256) void outproj_kernel(
        const bf16* __restrict__ AO, const bf16* __restrict__ Wob,
        const float* __restrict__ bo, float* __restrict__ out) {
    __shared__ bf16 lA[BM * BK], lB[BN * BK];
    const int bm = blockIdx.x * BM, bn = blockIdx.y * BN;
    f32x4 acc[4][4] = {};
    gemm_core(AO, Wob, bm, bn, D_MODEL, lA, lB, acc);

    const int lane = threadIdx.x & 63, w = threadIdx.x >> 6;
    const int wr = w >> 1, wc = w & 1, r = lane & 15, g = lane >> 4;
    #pragma unroll
    for (int n = 0; n < 4; ++n) {
        const int col = bn + wc * 64 + n * 16 + r;
        const float bvl = bo[col];
        #pragma unroll
        for (int m = 0; m < 4; ++m)
            #pragma unroll
            for (int j = 0; j < 4; ++j) {
                const int row = bm + wr * 64 + m * 16 + g * 4 + j;
                out[(size_t)row * D_MODEL + col] = acc[m][n][j] + bvl;
            }
    }
}

// ---------------- fused masked flash attention: mask-only LDS double buffer ----------------
// R6 (proven): block-level LDS staging, line-granular global access. R7 lesson: full dbuf
// (72KB -> 2 blk/CU) regressed. R9 lesson: sched_barrier pinning + lgkmcnt asm regressed.
// R10: dbuf ONLY the mask (the HBM-cold stream): K 8 + V 8 + M x2 = 48KB -> 3 blk/CU kept.
// P's LDS is eliminated by reusing kbuf as P-scratch after a barrier closes all QK^T reads.
// Per tile: barrier; issue K/V(t); issue M(t+1); vmcnt(4) [FIFO: completes K/V(t) AND M(t),
// leaves M(t+1) in flight with a full tile-time to land]; barrier; QK^T; exp; barrier;
// P->kbuf; PV. No sched_barrier, no lgkmcnt asm — compiler schedules freely.
// Swapped QK^T (A=K, B=Q): lane (r,g) holds S[q=r][kv=n*16+g*4+j]. No max-subtraction
// (|S|<~10 after *0.125); row-sum deferred to 2 end shfl_xor.
__global__ __launch_bounds__(256, 3) void attn_kernel(
        const bf16* __restrict__ Qp, const bf16* __restrict__ Kp, const bf16* __restrict__ Vt,
        const unsigned int* __restrict__ mask, bf16* __restrict__ AO) {
    __shared__ char kbuf[8192];            // K tile [64 s][128B], chunk-swizzled; P-scratch late
    __shared__ char vbuf[8192];            // V^T tile [64 d][128B], chunk-swizzled
    __shared__ char mbuf[2][16384];        // mask tile dbuf [64 q][256B], chunk-swizzled
    const int lin = blockIdx.x + blockIdx.y * gridDim.x;
    const int xcd = lin & 7, pos = lin >> 3;
    const int bh  = xcd * 16 + (pos >> 4);
    const int qt  = pos & 15;
    const int b = bh >> 4, h = bh & 15;
    const int t = threadIdx.x, lane = t & 63, w = t >> 6;
    const int q0 = qt * 64;                // block q-tile; wave w owns rows w*16 + r
    const int r = lane & 15, g = lane >> 4;

    const char* __restrict__ Kb = (const char*)(Kp + (size_t)bh * SEQL * D_K);
    const char* __restrict__ Vb = (const char*)(Vt + (size_t)bh * D_K * SEQL);
    const char* __restrict__ Mb = (const char*)(mask + ((size_t)bh * SEQL + q0) * SEQL);

    // Q fragment (B-operand): lane holds Q[q=r][kk*32+g*8..+8]; loaded once
    const bf16* __restrict__ Qh = Qp + ((size_t)bh * SEQL + q0 + w * 16) * D_K;
    bf16x8 qf[2];
    #pragma unroll
    for (int kk = 0; kk < 2; ++kk)
        qf[kk] = *(const bf16x8*)(Qh + r * D_K + kk * 32 + g * 8);

    // ---- prologue: stage M(0) into mbuf[0] (4 gload_lds) ----
    #pragma unroll
    for (int i = 0; i < 4; ++i) {
        const int slot = i * 256 + t;
        const int row = slot >> 4, ch = slot & 15;
        const char* srcM = Mb + (size_t)row * (SEQL * 4) + ((ch * 16) ^ ((row & 7) << 4));
        __builtin_amdgcn_global_load_lds(
            (const __attribute__((address_space(1))) unsigned int*)srcM,
            (__attribute__((address_space(3))) unsigned int*)(mbuf[0] + i * 4096 + w * 1024),
            16, 0, 0);
    }

    f32x4 o[4] = {};              // O^T: o[n][j] = O[q=r][d = n*16 + g*4 + j]
    float psum = 0.f;
    char* P = kbuf + w * 2048;    // per-wave P scratch (reuses kbuf after barrier C)
    const int swz = (r & 7) << 4;

    for (int tt = 0; tt < NT; ++tt) {
        const int s0 = tt * 64;
        const int sn = (tt + 1 < NT) ? (tt + 1) * 64 : 0;   // clamped tail keeps counts const
        char* mcur = mbuf[tt & 1];
        char* mnxt = mbuf[(tt + 1) & 1];

        __builtin_amdgcn_s_barrier();   // A: all waves done reading prev tile's bufs
        // ---- issue K/V(tt) FIRST (4 loads) — FIFO position matters for vmcnt(4) ----
        #pragma unroll
        for (int i = 0; i < 2; ++i) {
            const int slot = i * 256 + t;
            const int row = slot >> 3, ch = slot & 7;
            const char* srcK = Kb + (size_t)(s0 + row) * 128 + ((ch * 16) ^ ((row & 7) << 4));
            const char* srcV = Vb + (size_t)row * (SEQL * 2) + s0 * 2 + ((ch * 16) ^ ((row & 7) << 4));
            __builtin_amdgcn_global_load_lds(
                (const __attribute__((address_space(1))) unsigned int*)srcK,
                (__attribute__((address_space(3))) unsigned int*)(kbuf + i * 4096 + w * 1024),
                16, 0, 0);
            __builtin_amdgcn_global_load_lds(
                (const __attribute__((address_space(1))) unsigned int*)srcV,
                (__attribute__((address_space(3))) unsigned int*)(vbuf + i * 4096 + w * 1024),
                16, 0, 0);
        }
        // ---- issue M(tt+1) (4 loads) — stays in flight across the wait+barrier ----
        #pragma unroll
        for (int i = 0; i < 4; ++i) {
            const int slot = i * 256 + t;
            const int row = slot >> 4, ch = slot & 15;
            const char* srcM = Mb + (size_t)row * (SEQL * 4) + sn * 4 + ((ch * 16) ^ ((row & 7) << 4));
            __builtin_amdgcn_global_load_lds(
                (const __attribute__((address_space(1))) unsigned int*)srcM,
                (__attribute__((address_space(3))) unsigned int*)(mnxt + i * 4096 + w * 1024),
                16, 0, 0);
        }
        // FIFO in-order completion: 4 remaining = M(tt+1); K/V(tt) and M(tt) are done.
        asm volatile("s_waitcnt vmcnt(4)" ::: "memory");
        __builtin_amdgcn_s_barrier();   // B: staging visible to all waves

        // ---- QK^T: sf[n][j] = S[q=r][kv = n*16 + g*4 + j] ----
        f32x4 sf[4] = {};
        __builtin_amdgcn_s_setprio(1);
        #pragma unroll
        for (int n = 0; n < 4; ++n) {
            #pragma unroll
            for (int kk = 0; kk < 2; ++kk) {
                const int krow = n * 16 + r;
                bf16x8 kf = *(const bf16x8*)(kbuf + krow * 128 + ((kk * 64 + g * 16) ^ swz));
                sf[n] = __builtin_amdgcn_mfma_f32_16x16x32_bf16(kf, qf[kk], sf[n], 0, 0, 0);
            }
        }
        __builtin_amdgcn_s_setprio(0);
        // ---- mask + exp (reads mcur; no max subtraction — masked lanes contribute 0) ----
        const int mrow = w * 16 + r;
        bf16x4 pb[4];
        #pragma unroll
        for (int n = 0; n < 4; ++n) {
            const uint4 mv = *(const uint4*)(mcur + mrow * 256 + ((n * 64 + g * 16) ^ swz));
            const float p0 = mv.x ? __expf(sf[n][0] * 0.125f) : 0.f;
            const float p1 = mv.y ? __expf(sf[n][1] * 0.125f) : 0.f;
            const float p2 = mv.z ? __expf(sf[n][2] * 0.125f) : 0.f;
            const float p3 = mv.w ? __expf(sf[n][3] * 0.125f) : 0.f;
            psum += (p0 + p1) + (p2 + p3);
            pb[n] = bf16x4{ (bf16)p0, (bf16)p1, (bf16)p2, (bf16)p3 };
        }
        __builtin_amdgcn_s_barrier();   // C: all waves' QK^T kbuf reads done -> P may clobber
        // ---- P -> kbuf scratch (per-wave 2KB quarter), then PV from vbuf ----
        #pragma unroll
        for (int n = 0; n < 4; ++n)
            *(bf16x4*)(P + ((r * 128 + n * 32 + g * 8) ^ swz)) = pb[n];
        bf16x8 pf0 = *(const bf16x8*)(P + ((r * 128 + 0 * 64 + g * 16) ^ swz));
        bf16x8 pf1 = *(const bf16x8*)(P + ((r * 128 + 1 * 64 + g * 16) ^ swz));
        __builtin_amdgcn_s_setprio(1);
        #pragma unroll
        for (int n = 0; n < 4; ++n) {
            const int vrow = n * 16 + r;
            bf16x8 vf0 = *(const bf16x8*)(vbuf + vrow * 128 + ((0 * 64 + g * 16) ^ swz));
            bf16x8 vf1 = *(const bf16x8*)(vbuf + vrow * 128 + ((1 * 64 + g * 16) ^ swz));
            o[n] = __builtin_amdgcn_mfma_f32_16x16x32_bf16(vf0, pf0, o[n], 0, 0, 0);
            o[n] = __builtin_amdgcn_mfma_f32_16x16x32_bf16(vf1, pf1, o[n], 0, 0, 0);
        }
        __builtin_amdgcn_s_setprio(0);
    }

    // deferred row-sum: lanes r, r+16, r+32, r+48 hold partials of row q=r
    psum += __shfl_xor(psum, 16);
    psum += __shfl_xor(psum, 32);
    const float inv = 1.0f / psum;

    const size_t rowbase = ((size_t)(b * SEQL + q0 + w * 16 + r)) * D_MODEL + h * D_K;
    #pragma unroll
    for (int n = 0; n < 4; ++n) {
        bf16x4 ob = { (bf16)(o[n][0] * inv), (bf16)(o[n][1] * inv),
                      (bf16)(o[n][2] * inv), (bf16)(o[n][3] * inv) };
        *(bf16x4*)(AO + rowbase + n * 16 + g * 4) = ob;
    }
}

// ---------------- launch ----------------
extern "C" void kernel_launch(void* const* d_in, const int* in_sizes, int n_in,
                              void* d_out, int out_size, void* d_ws, size_t ws_size,
                              hipStream_t stream) {
    const float* q    = (const float*)d_in[0];
    const float* k    = (const float*)d_in[1];
    const float* v    = (const float*)d_in[2];
    const unsigned int* mask = (const unsigned int*)d_in[3];
    const float* Wq = (const float*)d_in[4];
    const float* bq = (const float*)d_in[5];
    const float* Wk = (const float*)d_in[6];
    const float* bk = (const float*)d_in[7];
    const float* Wv = (const float*)d_in[8];
    const float* bv = (const float*)d_in[9];
    const float* Wo = (const float*)d_in[10];
    const float* bo = (const float*)d_in[11];

    char* ws = (char*)d_ws;
    const size_t MB = 1u << 20;
    bf16* qb  = (bf16*)(ws + 0 * MB);
    bf16* kb  = (bf16*)(ws + 16 * MB);
    bf16* vb  = (bf16*)(ws + 32 * MB);
    bf16* Wqb = (bf16*)(ws + 48 * MB);
    bf16* Wkb = (bf16*)(ws + 50 * MB);
    bf16* Wvb = (bf16*)(ws + 52 * MB);
    bf16* Wob = (bf16*)(ws + 54 * MB);
    bf16* Qp  = (bf16*)(ws + 56 * MB);
    bf16* Kp  = (bf16*)(ws + 72 * MB);
    bf16* Vt  = (bf16*)(ws + 88 * MB);
    bf16* AO  = (bf16*)(ws + 104 * MB);   // 120 MiB total

    Cvt7 c;
    c.s[0] = q;  c.d[0] = qb;  c.n[0] = MROWS * D_MODEL;
    c.s[1] = k;  c.d[1] = kb;  c.n[1] = MROWS * D_MODEL;
    c.s[2] = v;  c.d[2] = vb;  c.n[2] = MROWS * D_MODEL;
    c.s[3] = Wq; c.d[3] = Wqb; c.n[3] = D_MODEL * D_MODEL;
    c.s[4] = Wk; c.d[4] = Wkb; c.n[4] = D_MODEL * D_MODEL;
    c.s[5] = Wv; c.d[5] = Wvb; c.n[5] = D_MODEL * D_MODEL;
    c.s[6] = Wo; c.d[6] = Wob; c.n[6] = D_MODEL * D_MODEL;
    cvt7_kernel<<<dim3(1024, 7), 256, 0, stream>>>(c);

    proj3_kernel<<<dim3(MROWS / BM, D_MODEL / BN, 3), 256, 0, stream>>>(
        qb, kb, vb, Wqb, Wkb, Wvb, bq, bk, bv, Qp, Kp, Vt);

    attn_kernel<<<dim3(SEQL / 64, BATCH * NHEAD), 256, 0, stream>>>(Qp, Kp, Vt, mask, AO);

    outproj_kernel<<<dim3(MROWS / BM, D_MODEL / BN), 256, 0, stream>>>(AO, Wob, bo, (float*)d_out);
}

// Round 11
// 292.077 us; speedup vs baseline: 1.3072x; 1.0612x over previous
//
#include <hip/hip_runtime.h>

typedef __bf16 bf16;
typedef bf16 bf16x4 __attribute__((ext_vector_type(4)));
typedef bf16 bf16x8 __attribute__((ext_vector_type(8)));
typedef float f32x4 __attribute__((ext_vector_type(4)));

#define D_MODEL 1024
#define NHEAD   16
#define D_K     64
#define BATCH   8
#define SEQL    1024
#define MROWS   (BATCH*SEQL)   // 8192

// ---------------- f32 -> bf16 conversion (7 arrays in one launch) ----------------
struct Cvt7 {
    const float* s[7];
    bf16*        d[7];
    int          n[7];
};

__global__ __launch_bounds__(256) void cvt7_kernel(Cvt7 a) {
    const int y = blockIdx.y;
    const float* __restrict__ src = a.s[y];
    bf16* __restrict__ dst = a.d[y];
    const int n4 = a.n[y] >> 2;
    const int stride = gridDim.x * blockDim.x;
    for (int i = blockIdx.x * blockDim.x + threadIdx.x; i < n4; i += stride) {
        float4 v = ((const float4*)src)[i];
        bf16x4 o = { (bf16)v.x, (bf16)v.y, (bf16)v.z, (bf16)v.w };
        ((bf16x4*)dst)[i] = o;
    }
}

// ---------------- GEMM core (R1-proven m97 structure): C = A * B^T ----------------
// 128x128 tile, BK=32, 4 waves (2x2 of 64x64), global_load_lds w=16.
// R2 lesson: 256x256 tile regressed at N=1024 (4 col-tiles -> 1.5 blk/CU imbalance).
#define BM 128
#define BN 128
#define BK 32

__device__ __forceinline__ void gemm_core(const bf16* __restrict__ A, const bf16* __restrict__ B,
                                          int bm, int bn, int K,
                                          bf16* lA, bf16* lB, f32x4 (&acc)[4][4]) {
    const int t = threadIdx.x;
    const int lane = t & 63, w = t >> 6;
    const int wr = w >> 1, wc = w & 1;
    const int r = lane & 15, kb = lane >> 4;

    for (int k0 = 0; k0 < K; k0 += BK) {
        __syncthreads();
        #pragma unroll
        for (int i = 0; i < 2; ++i) {
            const int off = i * 4096 + w * 1024 + lane * 16;
            const int row = off >> 6;
            const int cb  = off & 63;
            const bf16* srcA = A + (size_t)(bm + row) * K + k0 + (cb >> 1);
            const bf16* srcB = B + (size_t)(bn + row) * K + k0 + (cb >> 1);
            __builtin_amdgcn_global_load_lds(
                (const __attribute__((address_space(1))) unsigned int*)srcA,
                (__attribute__((address_space(3))) unsigned int*)((char*)lA + i * 4096 + w * 1024),
                16, 0, 0);
            __builtin_amdgcn_global_load_lds(
                (const __attribute__((address_space(1))) unsigned int*)srcB,
                (__attribute__((address_space(3))) unsigned int*)((char*)lB + i * 4096 + w * 1024),
                16, 0, 0);
        }
        __syncthreads();

        bf16x8 af[4], bfr[4];
        #pragma unroll
        for (int m = 0; m < 4; ++m)
            af[m] = *(const bf16x8*)(lA + (wr * 64 + m * 16 + r) * BK + kb * 8);
        #pragma unroll
        for (int n = 0; n < 4; ++n)
            bfr[n] = *(const bf16x8*)(lB + (wc * 64 + n * 16 + r) * BK + kb * 8);
        #pragma unroll
        for (int m = 0; m < 4; ++m)
            #pragma unroll
            for (int n = 0; n < 4; ++n)
                acc[m][n] = __builtin_amdgcn_mfma_f32_16x16x32_bf16(af[m], bfr[n], acc[m][n], 0, 0, 0);
    }
}

// ---------------- Q/K/V projections (one launch, z = 0/1/2) ----------------
__global__ __launch_bounds__(256) void proj3_kernel(
        const bf16* __restrict__ xq, const bf16* __restrict__ xk, const bf16* __restrict__ xv,
        const bf16* __restrict__ Wqb, const bf16* __restrict__ Wkb, const bf16* __restrict__ Wvb,
        const float* __restrict__ bq, const float* __restrict__ bk, const float* __restrict__ bv,
        bf16* __restrict__ Qp, bf16* __restrict__ Kp, bf16* __restrict__ Vt) {
    __shared__ bf16 lA[BM * BK], lB[BN * BK];
    const int z = blockIdx.z;
    const bf16* A    = (z == 0) ? xq  : (z == 1) ? xk  : xv;
    const bf16* Bm   = (z == 0) ? Wqb : (z == 1) ? Wkb : Wvb;
    const float* bias = (z == 0) ? bq : (z == 1) ? bk  : bv;
    const int bm = blockIdx.x * BM, bn = blockIdx.y * BN;

    f32x4 acc[4][4] = {};
    gemm_core(A, Bm, bm, bn, D_MODEL, lA, lB, acc);

    const int lane = threadIdx.x & 63, w = threadIdx.x >> 6;
    const int wr = w >> 1, wc = w & 1, r = lane & 15, g = lane >> 4;
    #pragma unroll
    for (int n = 0; n < 4; ++n) {
        const int col = bn + wc * 64 + n * 16 + r;
        const float bvl = bias[col];
        const int h = col >> 6, d = col & 63;
        #pragma unroll
        for (int m = 0; m < 4; ++m) {
            #pragma unroll
            for (int j = 0; j < 4; ++j) {
                const int row = bm + wr * 64 + m * 16 + g * 4 + j;
                const float v = acc[m][n][j] + bvl;
                const int b = row >> 10, s = row & (SEQL - 1);
                const int bh = b * NHEAD + h;
                if (z == 0) {
                    Qp[((size_t)bh * SEQL + s) * D_K + d] = (bf16)v;
                } else if (z == 1) {
                    Kp[((size_t)bh * SEQL + s) * D_K + d] = (bf16)v;
                } else {
                    Vt[((size_t)bh * D_K + d) * SEQL + s] = (bf16)v;
                }
            }
        }
    }
}

// ---------------- output projection: out = AO * Wo^T + bo (f32 out) ----------------
__global__ __launch_bounds__(256) void outproj_kernel(
        const bf16* __restrict__ AO, const bf16* __restrict__ Wob,
        const float* __restrict__ bo, float* __restrict__ out) {
    __shared__ bf16 lA[BM * BK], lB[BN * BK];
    const int bm = blockIdx.x * BM, bn = blockIdx.y * BN;
    f32x4 acc[4][4] = {};
    gemm_core(AO, Wob, bm, bn, D_MODEL, lA, lB, acc);

    const int lane = threadIdx.x & 63, w = threadIdx.x >> 6;
    const int wr = w >> 1, wc = w & 1, r = lane & 15, g = lane >> 4;
    #pragma unroll
    for (int n = 0; n < 4; ++n) {
        const int col = bn + wc * 64 + n * 16 + r;
        const float bvl = bo[col];
        #pragma unroll
        for (int m = 0; m < 4; ++m)
            #pragma unroll
            for (int j = 0; j < 4; ++j) {
                const int row = bm + wr * 64 + m * 16 + g * 4 + j;
                out[(size_t)row * D_MODEL + col] = acc[m][n][j] + bvl;
            }
    }
}

// ---------------- fused masked flash attention: R8 structure, 4 blocks/CU ----------------
// R6/R8 (proven 292.5us): block-level LDS staging, line-granular global access, 40KB LDS,
// plain 2-barrier loop. R7/R9/R10 lessons: ALL explicit pipelining variants (full dbuf,
// reg-prefetch+sched pins, mask-only dbuf+counted vmcnt) regressed — the stage drain is
// hidden by CROSS-BLOCK overlap, not in-block scheduling. R11 single variable: raise that
// overlap. 40960B x 4 = 163840B = exactly 160KiB LDS, kernel fits <=128 VGPR ->
// __launch_bounds__(256,4) = 4 blocks/CU (was 3).
// Swapped QK^T (A=K, B=Q): lane (r,g) holds S[q=r][kv=n*16+g*4+j]. No max-subtraction
// (|S|<~10 after *0.125); row-sum deferred to 2 end shfl_xor.
__global__ __launch_bounds__(256, 4) void attn_kernel(
        const bf16* __restrict__ Qp, const bf16* __restrict__ Kp, const bf16* __restrict__ Vt,
        const unsigned int* __restrict__ mask, bf16* __restrict__ AO) {
    __shared__ char kbuf[8192];            // K tile [64 s][128B], chunk-swizzled
    __shared__ char vbuf[8192];            // V^T tile [64 d][128B], chunk-swizzled
    __shared__ char mbuf[16384];           // mask tile [64 q][256B], chunk-swizzled
    __shared__ bf16 plds[4][16 * 64];      // per-wave P tile (2 KiB each) -> 40KB total
    const int lin = blockIdx.x + blockIdx.y * gridDim.x;
    const int xcd = lin & 7, pos = lin >> 3;
    const int bh  = xcd * 16 + (pos >> 4);
    const int qt  = pos & 15;
    const int b = bh >> 4, h = bh & 15;
    const int t = threadIdx.x, lane = t & 63, w = t >> 6;
    const int q0 = qt * 64;                // block q-tile; wave w owns rows w*16 + r
    const int r = lane & 15, g = lane >> 4;

    const char* __restrict__ Kb = (const char*)(Kp + (size_t)bh * SEQL * D_K);
    const char* __restrict__ Vb = (const char*)(Vt + (size_t)bh * D_K * SEQL);
    const char* __restrict__ Mb = (const char*)(mask + ((size_t)bh * SEQL + q0) * SEQL);

    // Q fragment (B-operand): lane holds Q[q=r][kk*32+g*8..+8]; loaded once
    const bf16* __restrict__ Qh = Qp + ((size_t)bh * SEQL + q0 + w * 16) * D_K;
    bf16x8 qf[2];
    #pragma unroll
    for (int kk = 0; kk < 2; ++kk)
        qf[kk] = *(const bf16x8*)(Qh + r * D_K + kk * 32 + g * 8);

    f32x4 o[4] = {};              // O^T: o[n][j] = O[q=r][d = n*16 + g*4 + j]
    float psum = 0.f;
    char* P = (char*)plds[w];
    const int swz = (r & 7) << 4;

    for (int s0 = 0; s0 < SEQL; s0 += 64) {
        __syncthreads();   // prev tile's ds_reads done before overwrite
        // ---- stage K (2 instr), V (2 instr), M (4 instr); linear dest, swizzled source ----
        #pragma unroll
        for (int i = 0; i < 2; ++i) {
            const int slot = i * 256 + t;
            const int row = slot >> 3, ch = slot & 7;
            const char* srcK = Kb + (size_t)(s0 + row) * 128 + ((ch * 16) ^ ((row & 7) << 4));
            const char* srcV = Vb + (size_t)row * (SEQL * 2) + s0 * 2 + ((ch * 16) ^ ((row & 7) << 4));
            __builtin_amdgcn_global_load_lds(
                (const __attribute__((address_space(1))) unsigned int*)srcK,
                (__attribute__((address_space(3))) unsigned int*)(kbuf + i * 4096 + w * 1024),
                16, 0, 0);
            __builtin_amdgcn_global_load_lds(
                (const __attribute__((address_space(1))) unsigned int*)srcV,
                (__attribute__((address_space(3))) unsigned int*)(vbuf + i * 4096 + w * 1024),
                16, 0, 0);
        }
        #pragma unroll
        for (int i = 0; i < 4; ++i) {
            const int slot = i * 256 + t;
            const int row = slot >> 4, ch = slot & 15;
            const char* srcM = Mb + (size_t)row * (SEQL * 4) + s0 * 4 + ((ch * 16) ^ ((row & 7) << 4));
            __builtin_amdgcn_global_load_lds(
                (const __attribute__((address_space(1))) unsigned int*)srcM,
                (__attribute__((address_space(3))) unsigned int*)(mbuf + i * 4096 + w * 1024),
                16, 0, 0);
        }
        __syncthreads();   // staging visible (compiler drains vmcnt before barrier)

        // ---- QK^T: sf[n][j] = S[q=r][kv = n*16 + g*4 + j] ----
        f32x4 sf[4] = {};
        __builtin_amdgcn_s_setprio(1);
        #pragma unroll
        for (int n = 0; n < 4; ++n) {
            #pragma unroll
            for (int kk = 0; kk < 2; ++kk) {
                const int krow = n * 16 + r;
                bf16x8 kf = *(const bf16x8*)(kbuf + krow * 128 + ((kk * 64 + g * 16) ^ swz));
                sf[n] = __builtin_amdgcn_mfma_f32_16x16x32_bf16(kf, qf[kk], sf[n], 0, 0, 0);
            }
        }
        __builtin_amdgcn_s_setprio(0);
        // ---- mask + exp (no max subtraction; masked lanes contribute exactly 0) ----
        const int mrow = w * 16 + r;
        #pragma unroll
        for (int n = 0; n < 4; ++n) {
            const uint4 mv = *(const uint4*)(mbuf + mrow * 256 + ((n * 64 + g * 16) ^ swz));
            const float p0 = mv.x ? __expf(sf[n][0] * 0.125f) : 0.f;
            const float p1 = mv.y ? __expf(sf[n][1] * 0.125f) : 0.f;
            const float p2 = mv.z ? __expf(sf[n][2] * 0.125f) : 0.f;
            const float p3 = mv.w ? __expf(sf[n][3] * 0.125f) : 0.f;
            psum += (p0 + p1) + (p2 + p3);
            bf16x4 pb = { (bf16)p0, (bf16)p1, (bf16)p2, (bf16)p3 };
            *(bf16x4*)(P + ((r * 128 + n * 32 + g * 8) ^ swz)) = pb;
        }
        // ---- PV: o[n] += V^T[d-block n] * P^T (P round-trip via per-wave LDS) ----
        bf16x8 pf0 = *(const bf16x8*)(P + ((r * 128 + 0 * 64 + g * 16) ^ swz));
        bf16x8 pf1 = *(const bf16x8*)(P + ((r * 128 + 1 * 64 + g * 16) ^ swz));
        __builtin_amdgcn_s_setprio(1);
        #pragma unroll
        for (int n = 0; n < 4; ++n) {
            const int vrow = n * 16 + r;
            bf16x8 vf0 = *(const bf16x8*)(vbuf + vrow * 128 + ((0 * 64 + g * 16) ^ swz));
            bf16x8 vf1 = *(const bf16x8*)(vbuf + vrow * 128 + ((1 * 64 + g * 16) ^ swz));
            o[n] = __builtin_amdgcn_mfma_f32_16x16x32_bf16(vf0, pf0, o[n], 0, 0, 0);
            o[n] = __builtin_amdgcn_mfma_f32_16x16x32_bf16(vf1, pf1, o[n], 0, 0, 0);
        }
        __builtin_amdgcn_s_setprio(0);
    }

    // deferred row-sum: lanes r, r+16, r+32, r+48 hold partials of row q=r
    psum += __shfl_xor(psum, 16);
    psum += __shfl_xor(psum, 32);
    const float inv = 1.0f / psum;

    const size_t rowbase = ((size_t)(b * SEQL + q0 + w * 16 + r)) * D_MODEL + h * D_K;
    #pragma unroll
    for (int n = 0; n < 4; ++n) {
        bf16x4 ob = { (bf16)(o[n][0] * inv), (bf16)(o[n][1] * inv),
                      (bf16)(o[n][2] * inv), (bf16)(o[n][3] * inv) };
        *(bf16x4*)(AO + rowbase + n * 16 + g * 4) = ob;
    }
}

// ---------------- launch ----------------
extern "C" void kernel_launch(void* const* d_in, const int* in_sizes, int n_in,
                              void* d_out, int out_size, void* d_ws, size_t ws_size,
                              hipStream_t stream) {
    const float* q    = (const float*)d_in[0];
    const float* k    = (const float*)d_in[1];
    const float* v    = (const float*)d_in[2];
    const unsigned int* mask = (const unsigned int*)d_in[3];
    const float* Wq = (const float*)d_in[4];
    const float* bq = (const float*)d_in[5];
    const float* Wk = (const float*)d_in[6];
    const float* bk = (const float*)d_in[7];
    const float* Wv = (const float*)d_in[8];
    const float* bv = (const float*)d_in[9];
    const float* Wo = (const float*)d_in[10];
    const float* bo = (const float*)d_in[11];

    char* ws = (char*)d_ws;
    const size_t MB = 1u << 20;
    bf16* qb  = (bf16*)(ws + 0 * MB);
    bf16* kb  = (bf16*)(ws + 16 * MB);
    bf16* vb  = (bf16*)(ws + 32 * MB);
    bf16* Wqb = (bf16*)(ws + 48 * MB);
    bf16* Wkb = (bf16*)(ws + 50 * MB);
    bf16* Wvb = (bf16*)(ws + 52 * MB);
    bf16* Wob = (bf16*)(ws + 54 * MB);
    bf16* Qp  = (bf16*)(ws + 56 * MB);
    bf16* Kp  = (bf16*)(ws + 72 * MB);
    bf16* Vt  = (bf16*)(ws + 88 * MB);
    bf16* AO  = (bf16*)(ws + 104 * MB);   // 120 MiB total

    Cvt7 c;
    c.s[0] = q;  c.d[0] = qb;  c.n[0] = MROWS * D_MODEL;
    c.s[1] = k;  c.d[1] = kb;  c.n[1] = MROWS * D_MODEL;
    c.s[2] = v;  c.d[2] = vb;  c.n[2] = MROWS * D_MODEL;
    c.s[3] = Wq; c.d[3] = Wqb; c.n[3] = D_MODEL * D_MODEL;
    c.s[4] = Wk; c.d[4] = Wkb; c.n[4] = D_MODEL * D_MODEL;
    c.s[5] = Wv; c.d[5] = Wvb; c.n[5] = D_MODEL * D_MODEL;
    c.s[6] = Wo; c.d[6] = Wob; c.n[6] = D_MODEL * D_MODEL;
    cvt7_kernel<<<dim3(1024, 7), 256, 0, stream>>>(c);

    proj3_kernel<<<dim3(MROWS / BM, D_MODEL / BN, 3), 256, 0, stream>>>(
        qb, kb, vb, Wqb, Wkb, Wvb, bq, bk, bv, Qp, Kp, Vt);

    attn_kernel<<<dim3(SEQL / 64, BATCH * NHEAD), 256, 0, stream>>>(Qp, Kp, Vt, mask, AO);

    outproj_kernel<<<dim3(MROWS / BM, D_MODEL / BN), 256, 0, stream>>>(AO, Wob, bo, (float*)d_out);
}